// Round 3
// baseline (59.622 us; speedup 1.0000x reference)
//
#include <hip/hip_runtime.h>
#include <hip/hip_bf16.h>

#define N_N 128
#define N_C 7
#define N_H 96
#define N_W 192
#define HW (N_H * N_W)            // 18432
#define CHW (N_C * HW)            // 129024
#define NHW (N_N * HW)            // 2359296
#define NPTS 100
#define NK (N_N * N_C)            // 896
#define NK2 (NK / 2)              // 448 float2 per row
#define BG_BLOCKS 1024
#define SIGMA_F 2.0f

// ---------------- kernel A --------------------------------------------------
// blocks 0..1023   : BCE-with-logits partial sums over channel 0
// blocks 1024..1123: gather row i (transposed) + term1[i]
// block  1124      : zero the K2 accumulators
__global__ __launch_bounds__(256) void fusedA_kernel(
        const float* __restrict__ in, const float* __restrict__ tg,
        const int* __restrict__ px, const int* __restrict__ py,
        double* __restrict__ bgpart,        // [1024]
        float* __restrict__ Pt,             // [100][896]
        float* __restrict__ Gt,             // [100][896]
        float* __restrict__ term1,          // [100]
        double* __restrict__ klacc,         // [1]
        int* __restrict__ cntacc,           // [1]
        int* __restrict__ done) {           // [1]
    __shared__ float sdata[256];
    const int b = blockIdx.x;
    const int t = threadIdx.x;

    if (b == BG_BLOCKS + NPTS) {
        if (t == 0) { *klacc = 0.0; *cntacc = 0; *done = 0; }
        return;
    }

    if (b < BG_BLOCKS) {
        const int NV = NHW / 4;               // 589824
        const int HV = HW / 4;                // 4608
        const int CV = CHW / 4;               // 32256
        const float4* in4 = (const float4*)in;
        const float4* tg4 = (const float4*)tg;
        float s = 0.0f;
        for (int e = b * 256 + t; e < NV; e += BG_BLOCKS * 256) {
            int n = e / HV;
            int r = e - n * HV;
            float4 x4 = in4[n * CV + r];
            float4 t4 = tg4[n * CV + r];
            const float* xp = &x4.x;
            const float* tp = &t4.x;
#pragma unroll
            for (int q = 0; q < 4; ++q) {
                float x = xp[q], tt = tp[q];
                s += fmaxf(x, 0.0f) - x * tt + log1pf(expf(-fabsf(x)));
            }
        }
        sdata[t] = s;
        __syncthreads();
        for (int off = 128; off > 0; off >>= 1) {
            if (t < off) sdata[t] += sdata[t + off];
            __syncthreads();
        }
        if (t == 0) bgpart[b] = (double)sdata[0];
    } else {
        const int i = b - BG_BLOCKS;          // 0..99
        const int base = py[i] * N_W + px[i];
        float s = 0.0f;
        for (int k = t; k < NK; k += 256) {
            int n = k / N_C;
            int c = k - n * N_C;
            int off = n * CHW + c * HW + base;
            float p = in[off];
            float g = tg[off];
            Pt[i * NK + k] = p;
            Gt[i * NK + k] = g;
            s += (p > 0.0f) ? p * logf(p) : 0.0f;
        }
        sdata[t] = s;
        __syncthreads();
        for (int off = 128; off > 0; off >>= 1) {
            if (t < off) sdata[t] += sdata[t + off];
            __syncthreads();
        }
        if (t == 0) term1[i] = sdata[0];
    }
}

// ---------------- kernel B: pairs + in-kernel finalization ------------------
// 100 blocks, block i owns all pairs (i, j=0..99). Last block writes out.
__global__ __launch_bounds__(256) void pairsfin_kernel(
        const float* __restrict__ Pt, const float* __restrict__ Gt,
        const float* __restrict__ term1,
        const int* __restrict__ px, const int* __restrict__ py,
        const double* __restrict__ bgpart,   // [1024]
        double* __restrict__ klacc,
        int* __restrict__ cntacc,
        int* __restrict__ done,
        float* __restrict__ out) {
    __shared__ float2 sP[NK2];
    __shared__ float2 sG[NK2];
    __shared__ double skl[4];
    __shared__ int scnt[4];
    __shared__ int slast;
    __shared__ double sred[256];

    const int i = blockIdx.x;             // 0..99
    const int t = threadIdx.x;
    const int w = t >> 6;
    const int lane = t & 63;
    const float2* Pt2 = (const float2*)Pt;
    const float2* Gt2 = (const float2*)Gt;

    // stage row i in LDS
    for (int q = t; q < NK2; q += 256) {
        sP[q] = Pt2[i * NK2 + q];
        sG[q] = Gt2[i * NK2 + q];
    }
    __syncthreads();

    const float t1i = term1[i];
    const int pxi = px[i], pyi = py[i];
    double kl = 0.0;
    int cnt = 0;

    for (int jj = 0; jj < 25; ++jj) {     // wave w handles j = w + 4*jj
        const int j = w + 4 * jj;
        float cross = 0.0f;
        int eqf = 1;
#pragma unroll
        for (int it = 0; it < 7; ++it) {  // 448 float2 / 64 lanes
            int q = lane + it * 64;
            float2 pj = Pt2[j * NK2 + q];
            float2 gj = Gt2[j * NK2 + q];
            float2 pi = sP[q];
            float2 gi = sG[q];
            cross = fmaf(pi.x, pj.x, cross);
            cross = fmaf(pi.y, pj.y, cross);
            eqf &= (gi.x == gj.x) & (gi.y == gj.y);
        }
#pragma unroll
        for (int m = 32; m >= 1; m >>= 1) cross += __shfl_xor(cross, m);
        int alleq = __all(eqf);
        if (lane == 0) {
            float Dij = (term1[j] - cross) * (1.0f / (float)N_N);
            float Dji = (t1i - cross) * (1.0f / (float)N_N);
            float L = alleq ? (Dij + Dji)
                            : (float)(N_N * N_C) *
                              (fmaxf(SIGMA_F - Dij, 0.0f) + fmaxf(SIGMA_F - Dji, 0.0f));
            bool mask = (i != j) && (pxi != px[j]) && (pyi != py[j]);
            if (mask) { kl += (double)L; cnt += 1; }
        }
    }

    if (lane == 0) { skl[w] = kl; scnt[w] = cnt; }
    __syncthreads();

    if (t == 0) {
        double klblock = skl[0] + skl[1] + skl[2] + skl[3];
        int cntblock = scnt[0] + scnt[1] + scnt[2] + scnt[3];
        atomicAdd(klacc, klblock);
        atomicAdd(cntacc, cntblock);
        __threadfence();
        int old = atomicAdd(done, 1);
        slast = (old == NPTS - 1) ? 1 : 0;
    }
    __syncthreads();

    if (slast) {
        // last block: finalize
        double s = 0.0;
        for (int q = t; q < BG_BLOCKS; q += 256) s += bgpart[q];
        sred[t] = s;
        __syncthreads();
        for (int off = 128; off > 0; off >>= 1) {
            if (t < off) sred[t] += sred[t + off];
            __syncthreads();
        }
        if (t == 0) {
            __threadfence();
            double klv = *(volatile double*)klacc;
            int cntv = *(volatile int*)cntacc;
            double bg_loss = sred[0] / (double)NHW;
            out[0] = (float)(bg_loss + klv / (double)cntv);
        }
    }
}

// ---------------- launch ---------------------------------------------------
extern "C" void kernel_launch(void* const* d_in, const int* in_sizes, int n_in,
                              void* d_out, int out_size, void* d_ws, size_t ws_size,
                              hipStream_t stream) {
    const float* inputs  = (const float*)d_in[0];
    const float* targets = (const float*)d_in[1];
    const int*   px      = (const int*)d_in[2];
    const int*   py      = (const int*)d_in[3];
    float* out = (float*)d_out;

    char* ws = (char*)d_ws;
    double* bgpart = (double*)ws;                              // 1024*8 = 8192
    float*  Pt     = (float*)(ws + 8192);                      // 358400
    float*  Gt     = (float*)(ws + 8192 + 358400);             // 358400
    float*  term1  = (float*)(ws + 8192 + 2 * 358400);         // 512 (pad)
    double* klacc  = (double*)(ws + 8192 + 2 * 358400 + 512);  // 8
    int*    cntacc = (int*)(ws + 8192 + 2 * 358400 + 512 + 8);
    int*    done   = (int*)(ws + 8192 + 2 * 358400 + 512 + 16);

    fusedA_kernel<<<BG_BLOCKS + NPTS + 1, 256, 0, stream>>>(
        inputs, targets, px, py, bgpart, Pt, Gt, term1, klacc, cntacc, done);
    pairsfin_kernel<<<NPTS, 256, 0, stream>>>(
        Pt, Gt, term1, px, py, bgpart, klacc, cntacc, done, out);
}